// Round 15
// baseline (1873.678 us; speedup 1.0000x reference)
//
#include <hip/hip_runtime.h>

typedef unsigned short u16;
typedef unsigned int u32;
typedef __bf16 bfx8 __attribute__((ext_vector_type(8)));
typedef float f32x4 __attribute__((ext_vector_type(4)));

constexpr int BB = 64;     // batch
constexpr int TT = 64;     // time
constexpr int EE = 2048;   // x feature
constexpr int DD = 4096;   // deter
constexpr int GG = 8;      // groups
constexpr int H3 = 3 * DD;       // 12288
constexpr int CH = H3 / GG;      // 1536
constexpr float EPSf = 1e-4f;

static __device__ __forceinline__ u16 f2bf(float f) {
  u32 u = __builtin_bit_cast(u32, f);
  u32 r = (u + 0x7fffu + ((u >> 16) & 1u)) >> 16;
  return (u16)r;
}
static __device__ __forceinline__ float bf2f(u16 h) {
  return __builtin_bit_cast(float, (u32)h << 16);
}

// async global->LDS, 16B per lane; LDS dest = wave-uniform base + lane*16
#define GLOAD_LDS16(gp, lp)                                                    \
  __builtin_amdgcn_global_load_lds(                                           \
      (const __attribute__((address_space(1))) void*)(gp),                    \
      (__attribute__((address_space(3))) void*)(lp), 16, 0, 0)

// ---------------- prepass kernels ----------------

__global__ void __launch_bounds__(256) k_f2b(const float* __restrict__ in,
                                             u16* __restrict__ out, int n4) {
  int i = blockIdx.x * 256 + threadIdx.x;
  int stride = gridDim.x * 256;
  for (; i < n4; i += stride) {
    float4 v = ((const float4*)in)[i];
    uint2 o;
    o.x = (u32)f2bf(v.x) | ((u32)f2bf(v.y) << 16);
    o.y = (u32)f2bf(v.z) | ((u32)f2bf(v.w) << 16);
    ((uint2*)out)[i] = o;
  }
}

__global__ void __launch_bounds__(256) k_initdet(const float* __restrict__ d0,
                                                 float* __restrict__ dF,
                                                 u16* __restrict__ dB, int n4) {
  int i = blockIdx.x * 256 + threadIdx.x;
  if (i < n4) {
    float4 v = ((const float4*)d0)[i];
    ((float4*)dF)[i] = v;
    uint2 o;
    o.x = (u32)f2bf(v.x) | ((u32)f2bf(v.y) << 16);
    o.y = (u32)f2bf(v.z) | ((u32)f2bf(v.w) << 16);
    ((uint2*)dB)[i] = o;
  }
}

// in [R][C] f32 -> out [C][R] bf16  (batched over blockIdx.z)
__global__ void __launch_bounds__(256) k_transpose_f2b(const float* __restrict__ in,
                                                       u16* __restrict__ out,
                                                       int R, int C) {
  __shared__ float tile[32][33];
  size_t base = (size_t)blockIdx.z * R * C;
  in += base; out += base;
  int tx = threadIdx.x & 31, ty = threadIdx.x >> 5;
  int r0 = blockIdx.y * 32, c0 = blockIdx.x * 32;
#pragma unroll
  for (int i = 0; i < 4; i++) {
    int rr = ty * 4 + i;
    tile[rr][tx] = in[(size_t)(r0 + rr) * C + (c0 + tx)];
  }
  __syncthreads();
#pragma unroll
  for (int i = 0; i < 4; i++) {
    int cc = ty * 4 + i;
    out[(size_t)(c0 + cc) * R + (r0 + tx)] = f2bf(tile[tx][cc]);
  }
}

// ---------------- P1: Xproj = x @ W2 + b_in -> bf16 ----------------
// m97 structure + T2 LDS swizzle (round-14 proven) + T1 XCD-aware block
// swizzle (m192 formula; nwg=1024, %8==0 -> bijective). Each XCD gets 4
// contiguous tile-rows -> A panels L2-resident. Pure block reorder ->
// bit-identical output.

__global__ void __launch_bounds__(256) k_p1(const u16* __restrict__ A,  // [4096][2048]
                                            const u16* __restrict__ B,  // [4096][6144] (W2T at col 0)
                                            const float* __restrict__ bias,
                                            u16* __restrict__ C) {      // [4096][4096] bf16
  __shared__ u16 As[128 * 64];   // 16 KB, linear [row][64]
  __shared__ u16 Bs[128 * 64];   // 16 KB
  const int tid = threadIdx.x;
  const int bid = blockIdx.x;
  const int swz = (bid & 7) * 128 + (bid >> 3);   // XCD-aware remap
  const int m0 = (swz >> 5) * 128, n0 = (swz & 31) * 128;
  const int w = tid >> 6, lane = tid & 63;
  const int wr = w >> 1, wc = w & 1;
  const int lr = lane & 15, lk = (lane >> 4) * 8;
  // staging: chunk = w*4+i (8 rows x 8 slots); lane covers row chunk*8+(l>>3),
  // dest slot l&7; SOURCE col slot = (l&7) ^ (row&7) = (l&7) ^ (l>>3).
  const int lrow = lane >> 3;
  const int lcol = (((lane & 7) ^ (lane >> 3)) << 3);
  const u16* gA[4];
  const u16* gB[4];
  u16* lA[4];
  u16* lB[4];
#pragma unroll
  for (int i = 0; i < 4; i++) {
    const int chunk = w * 4 + i;
    const int row = chunk * 8 + lrow;
    gA[i] = A + (size_t)(m0 + row) * EE + lcol;
    gB[i] = B + (size_t)(n0 + row) * (DD + EE) + lcol;
    lA[i] = &As[chunk * 512];
    lB[i] = &Bs[chunk * 512];
  }

  f32x4 acc[4][4] = {};

  for (int kt = 0; kt < EE; kt += 64) {
#pragma unroll
    for (int i = 0; i < 4; i++) {
      GLOAD_LDS16(gA[i] + kt, lA[i]);
      GLOAD_LDS16(gB[i] + kt, lB[i]);
    }
    __syncthreads();   // drains vmcnt (async loads) before LDS reads
#pragma unroll
    for (int kk = 0; kk < 64; kk += 32) {
      const int sl = (((kk + lk) >> 3) ^ (lr & 7)) << 3;  // swizzled slot offset
      bfx8 av[4], bv[4];
#pragma unroll
      for (int mi = 0; mi < 4; mi++)
        av[mi] = *(const bfx8*)&As[(wr * 64 + mi * 16 + lr) * 64 + sl];
#pragma unroll
      for (int ni = 0; ni < 4; ni++)
        bv[ni] = *(const bfx8*)&Bs[(wc * 64 + ni * 16 + lr) * 64 + sl];
#pragma unroll
      for (int mi = 0; mi < 4; mi++)
#pragma unroll
        for (int ni = 0; ni < 4; ni++)
          acc[mi][ni] = __builtin_amdgcn_mfma_f32_16x16x32_bf16(av[mi], bv[ni], acc[mi][ni], 0, 0, 0);
    }
    __syncthreads();
  }

  const int rq = (lane >> 4) * 4;
#pragma unroll
  for (int mi = 0; mi < 4; mi++) {
#pragma unroll
    for (int ni = 0; ni < 4; ni++) {
      const int n = n0 + wc * 64 + ni * 16 + lr;
      const float bias_v = bias[n];
#pragma unroll
      for (int r = 0; r < 4; r++) {
        const int m = m0 + wr * 64 + mi * 16 + rq + r;
        C[(size_t)m * DD + n] = f2bf(acc[mi][ni][r] + bias_v);
      }
    }
  }
}

// ---------------- scan kernels ----------------
// kA: part[kc] = dB @ W1[:, kc*1024 .. +1024]   (round-14 proven body)
// global_load_lds staging, linear [64][128] LDS, dbuf, 1 barrier/iter,
// both-sides XOR swizzle.

__global__ void __launch_bounds__(512) kA(const u16* __restrict__ dB,
                                          const u16* __restrict__ WT,
                                          float* __restrict__ part) {
  __shared__ u16 As[2 * 8192];   // 32 KB
  __shared__ u16 Bs[2 * 8192];   // 32 KB
  const int tid = threadIdx.x;
  const int n0 = blockIdx.x * 64;
  const int k0 = blockIdx.y * 1024;
  const int w = tid >> 6, lane = tid & 63;
  const int wr = w >> 1, wc = w & 1;
  const int lr = lane & 15, lk = (lane >> 4) * 8, rq = (lane >> 4) * 4;
  const int r0 = w * 4 + (lane >> 4);          // rows 0..31 (half 0)
  const int r1 = r0 + 32;                      // rows 32..63 (half 1)
  const int s0 = (((lane & 15) ^ (r0 & 15)) << 3);
  const int s1 = (((lane & 15) ^ (r1 & 15)) << 3);
  const u16* gA0 = dB + (size_t)r0 * DD + k0 + s0;
  const u16* gA1 = dB + (size_t)r1 * DD + k0 + s1;
  const u16* gB0 = WT + (size_t)(n0 + r0) * (DD + EE) + k0 + s0;
  const u16* gB1 = WT + (size_t)(n0 + r1) * (DD + EE) + k0 + s1;
  u16* dA0 = &As[0] + w * 512;
  u16* dA1 = &As[0] + 4096 + w * 512;
  u16* dB0 = &Bs[0] + w * 512;
  u16* dB1 = &Bs[0] + 4096 + w * 512;

  f32x4 acc[2] = {};
  GLOAD_LDS16(gA0, dA0);
  GLOAD_LDS16(gA1, dA1);
  GLOAD_LDS16(gB0, dB0);
  GLOAD_LDS16(gB1, dB1);
  __syncthreads();

  for (int kt = 0; kt < 8; ++kt) {
    const int p = kt & 1, q = p ^ 1;
    if (kt < 7) {
      const int ko = (kt + 1) * 128;
      GLOAD_LDS16(gA0 + ko, dA0 + q * 8192);
      GLOAD_LDS16(gA1 + ko, dA1 + q * 8192);
      GLOAD_LDS16(gB0 + ko, dB0 + q * 8192);
      GLOAD_LDS16(gB1 + ko, dB1 + q * 8192);
    }
    const u16* ab = &As[p * 8192];
    const u16* bb = &Bs[p * 8192];
#pragma unroll
    for (int kk = 0; kk < 128; kk += 32) {
      const int sl = ((((kk + lk) >> 3)) ^ lr) << 3;   // swizzled slot offset
      bfx8 av = *(const bfx8*)&ab[(wr * 16 + lr) * 128 + sl];
#pragma unroll
      for (int ni = 0; ni < 2; ni++) {
        bfx8 bv = *(const bfx8*)&bb[(wc * 32 + ni * 16 + lr) * 128 + sl];
        acc[ni] = __builtin_amdgcn_mfma_f32_16x16x32_bf16(av, bv, acc[ni], 0, 0, 0);
      }
    }
    __syncthreads();
  }

  float* Pp = part + (size_t)blockIdx.y * BB * DD;
#pragma unroll
  for (int ni = 0; ni < 2; ni++)
#pragma unroll
    for (int r = 0; r < 4; r++)
      Pp[(size_t)(wr * 16 + rq + r) * DD + n0 + wc * 32 + ni * 16 + lr] = acc[ni][r];
}

// kB: y = silu(rms(sum_kc part + Xproj_t) * scale_in) -> bf16   grid 64 x 512 thr
__global__ void __launch_bounds__(512) kB(const float* __restrict__ part,
                                          const u16* __restrict__ Xproj,
                                          const float* __restrict__ scale_in,
                                          u16* __restrict__ ybf, int t) {
  const int b = blockIdx.x, tid = threadIdx.x;
  const int w = tid >> 6, lane = tid & 63;
  __shared__ float sred[8];
  const u16* xp = Xproj + ((size_t)b * TT + t) * DD + tid * 8;
  const float* pb = part + (size_t)b * DD + tid * 8;
  float v[8];
  uint4 x0 = *(const uint4*)(xp);
#pragma unroll
  for (int j = 0; j < 8; j++) v[j] = bf2f(((const u16*)&x0)[j]);
#pragma unroll
  for (int kc = 0; kc < 4; kc++) {
    const float* p = pb + (size_t)kc * BB * DD;
    float4 q0 = *(const float4*)(p);
    float4 q1 = *(const float4*)(p + 4);
    v[0] += q0.x; v[1] += q0.y; v[2] += q0.z; v[3] += q0.w;
    v[4] += q1.x; v[5] += q1.y; v[6] += q1.z; v[7] += q1.w;
  }
  float ss = 0.f;
#pragma unroll
  for (int j = 0; j < 8; j++) ss += v[j] * v[j];
#pragma unroll
  for (int o = 32; o > 0; o >>= 1) ss += __shfl_down(ss, o);
  if (lane == 0) sred[w] = ss;
  __syncthreads();
  float tot = 0.f;
#pragma unroll
  for (int i = 0; i < 8; i++) tot += sred[i];
  const float r = rsqrtf(tot / (float)DD + EPSf);
  const float* sc = scale_in + tid * 8;
  u32 pk[4];
#pragma unroll
  for (int j = 0; j < 4; j++) {
    float a = v[2 * j] * r * sc[2 * j];
    float bq = v[2 * j + 1] * r * sc[2 * j + 1];
    a = a / (1.f + __expf(-a));
    bq = bq / (1.f + __expf(-bq));
    pk[j] = (u32)f2bf(a) | ((u32)f2bf(bq) << 16);
  }
  *(uint4*)(ybf + (size_t)b * DD + tid * 8) = make_uint4(pk[0], pk[1], pk[2], pk[3]);
}

// kC: z = blockdiag(y @ Wblk) + b_blk -> zbuf f32; fused per-row sumsq -> zsq[192][64]
// NEW: global_load_lds staging (async DMA), linear [64][64] LDS, dbuf,
// 1 barrier/iter, both-sides XOR swizzle (mirror of kA). MFMA inputs
// bit-identical to round 14.

__global__ void __launch_bounds__(256) kC(const u16* __restrict__ ybf,
                                          const u16* __restrict__ WbT,
                                          const float* __restrict__ b_blk,
                                          float* __restrict__ zbuf,
                                          float* __restrict__ zsq) {
  __shared__ u16 As[2 * 4096];   // 16 KB (2 buf x [64][64])
  __shared__ u16 Bs[2 * 4096];   // 16 KB
  const int tid = threadIdx.x;
  const int wg = blockIdx.x;
  const int n0g = wg * 64;
  const int g = n0g / CH, nl = n0g % CH;
  const int w = tid >> 6, lane = tid & 63;
  const int lr = lane & 15, lk = (lane >> 4) * 8, rq = (lane >> 4) * 4;
  // staging: issue i covers rows i*32 + w*8 + (l>>3); dest slot = l&7;
  // source col slot = (l&7) ^ (row&7).
  const int sr0 = w * 8 + (lane >> 3);        // rows 0..31
  const int sr1 = sr0 + 32;                   // rows 32..63
  const int c0 = (((lane & 7) ^ (sr0 & 7)) << 3);
  const int c1 = (((lane & 7) ^ (sr1 & 7)) << 3);
  const u16* gA0 = ybf + (size_t)sr0 * DD + g * 512 + c0;
  const u16* gA1 = ybf + (size_t)sr1 * DD + g * 512 + c1;
  const u16* gB0 = WbT + ((size_t)g * CH + nl + sr0) * 512 + c0;
  const u16* gB1 = WbT + ((size_t)g * CH + nl + sr1) * 512 + c1;
  u16* dA0 = &As[0] + w * 512;
  u16* dA1 = &As[0] + 2048 + w * 512;
  u16* dB0 = &Bs[0] + w * 512;
  u16* dB1 = &Bs[0] + 2048 + w * 512;

  f32x4 acc[4] = {};
  GLOAD_LDS16(gA0, dA0);
  GLOAD_LDS16(gA1, dA1);
  GLOAD_LDS16(gB0, dB0);
  GLOAD_LDS16(gB1, dB1);
  __syncthreads();

  for (int kt = 0; kt < 8; ++kt) {
    const int p = kt & 1, q = p ^ 1;
    if (kt < 7) {
      const int ko = (kt + 1) * 64;
      GLOAD_LDS16(gA0 + ko, dA0 + q * 4096);
      GLOAD_LDS16(gA1 + ko, dA1 + q * 4096);
      GLOAD_LDS16(gB0 + ko, dB0 + q * 4096);
      GLOAD_LDS16(gB1 + ko, dB1 + q * 4096);
    }
    const u16* ab = &As[p * 4096];
    const u16* bb = &Bs[p * 4096];
#pragma unroll
    for (int kk = 0; kk < 64; kk += 32) {
      const int sl = (((kk + lk) >> 3) ^ (lr & 7)) << 3;   // swizzled slot
      bfx8 av = *(const bfx8*)&ab[(w * 16 + lr) * 64 + sl];
#pragma unroll
      for (int ni = 0; ni < 4; ni++) {
        bfx8 bv = *(const bfx8*)&bb[(ni * 16 + lr) * 64 + sl];
        acc[ni] = __builtin_amdgcn_mfma_f32_16x16x32_bf16(av, bv, acc[ni], 0, 0, 0);
      }
    }
    __syncthreads();
  }

  float sq[4] = {0.f, 0.f, 0.f, 0.f};
#pragma unroll
  for (int ni = 0; ni < 4; ni++) {
    const int n = n0g + ni * 16 + lr;
    const float bias_v = b_blk[n];
#pragma unroll
    for (int r = 0; r < 4; r++) {
      const float zv = acc[ni][r] + bias_v;
      zbuf[(size_t)(w * 16 + rq + r) * H3 + n] = zv;
      sq[r] += zv * zv;
    }
  }
#pragma unroll
  for (int o = 1; o < 16; o <<= 1) {
#pragma unroll
    for (int r = 0; r < 4; r++) sq[r] += __shfl_xor(sq[r], o);
  }
  if (lr == 0) {
#pragma unroll
    for (int r = 0; r < 4; r++) zsq[(size_t)wg * 64 + w * 16 + rq + r] = sq[r];
  }
}

// kD: block-rms + gates + deter update + out write   grid 256 (= 64 b x 4 col-slices)
__global__ void __launch_bounds__(256) kD(const float* __restrict__ zbuf,
                                          const float* __restrict__ zsq,
                                          const float* __restrict__ sblk,
                                          float* __restrict__ dF,
                                          u16* __restrict__ dB,
                                          float* __restrict__ out, int t) {
  const int wg = blockIdx.x, tid = threadIdx.x;
  const int b = wg >> 2, s = wg & 3;
  __shared__ float sred[8];
  if (tid < 8) {
    float ssq = 0.f;
    const int j0 = tid * 24;
#pragma unroll
    for (int j = 0; j < 24; j++) ssq += zsq[(size_t)(j0 + j) * 64 + b];
    sred[tid] = rsqrtf(ssq / (float)CH + EPSf);
  }
  __syncthreads();
  const int d0 = s * 1024 + tid * 4;
  const float* zr = zbuf + (size_t)b * H3;
  float4 z0 = *(const float4*)(zr + d0);
  float4 z1 = *(const float4*)(zr + DD + d0);
  float4 z2 = *(const float4*)(zr + 2 * DD + d0);
  float4 dold = *(const float4*)(dF + (size_t)b * DD + d0);
  const float rsA = sred[d0 / CH];
  const float rsB = sred[(DD + d0) / CH];
  const float rsC = sred[(2 * DD + d0) / CH];
  float dn[4];
  const float* z0p = (const float*)&z0;
  const float* z1p = (const float*)&z1;
  const float* z2p = (const float*)&z2;
  const float* dop = (const float*)&dold;
#pragma unroll
  for (int e = 0; e < 4; e++) {
    const int dd = d0 + e;
    const float a0 = z0p[e] * rsA * sblk[dd];
    const float a1 = z1p[e] * rsB * sblk[DD + dd];
    const float a2 = z2p[e] * rsC * sblk[2 * DD + dd];
    const float reset = 1.f / (1.f + __expf(-a0));
    const float cand = tanhf(reset * a1);
    const float upd = 1.f / (1.f + __expf(-(a2 - 1.f)));
    dn[e] = upd * cand + (1.f - upd) * dop[e];
  }
  *(float4*)(dF + (size_t)b * DD + d0) = make_float4(dn[0], dn[1], dn[2], dn[3]);
  uint2 o;
  o.x = (u32)f2bf(dn[0]) | ((u32)f2bf(dn[1]) << 16);
  o.y = (u32)f2bf(dn[2]) | ((u32)f2bf(dn[3]) << 16);
  *(uint2*)(dB + (size_t)b * DD + d0) = o;
  *(float4*)(out + ((size_t)b * TT + t) * DD + d0) = make_float4(dn[0], dn[1], dn[2], dn[3]);
}

// ---------------- host ----------------

extern "C" void kernel_launch(void* const* d_in, const int* in_sizes, int n_in,
                              void* d_out, int out_size, void* d_ws, size_t ws_size,
                              hipStream_t stream) {
  (void)in_sizes; (void)n_in; (void)out_size; (void)ws_size;
  const float* x         = (const float*)d_in[0];  // [B,T,E]
  const float* deter0    = (const float*)d_in[1];  // [B,D]
  const float* W_in      = (const float*)d_in[2];  // [D+E, D]
  const float* b_in      = (const float*)d_in[3];  // [D]
  const float* scale_in  = (const float*)d_in[4];  // [D]
  const float* W_blk     = (const float*)d_in[5];  // [G, D/G, 3D/G]
  const float* b_blk     = (const float*)d_in[6];  // [3D]
  const float* scale_blk = (const float*)d_in[7];  // [G, 3D/G]
  float* out = (float*)d_out;

  char* ws = (char*)d_ws;
  size_t off = 0;
  auto alloc = [&](size_t bytes) -> void* {
    void* p = ws + off;
    off += (bytes + 255) & ~(size_t)255;
    return p;
  };
  u16*   WT    = (u16*)alloc((size_t)DD * (DD + EE) * 2);       // 50.3 MB
  u16*   WbT   = (u16*)alloc((size_t)GG * CH * (DD / GG) * 2);  // 12.6 MB
  u16*   Xproj = (u16*)alloc((size_t)BB * TT * DD * 2);         // 32 MB (bf16)
  float* dF    = (float*)alloc((size_t)BB * DD * 4);            // 1 MB
  u16*   dB    = (u16*)alloc((size_t)BB * DD * 2);              // 0.5 MB
  // scratch region: xbf (prepass/P1 only) aliases scan-only buffers
  char* scratch = (char*)alloc((size_t)BB * TT * EE * 2);       // 16.8 MB
  u16*   xbf  = (u16*)scratch;
  float* part = (float*)scratch;                                // 4 MB (4 splits)
  size_t o2 = (size_t)4 * BB * DD * 4;
  u16*   ybf  = (u16*)(scratch + o2);                           // 0.5 MB
  o2 += (size_t)BB * DD * 2;
  float* zbuf = (float*)(scratch + o2);                         // 3 MB
  o2 += (size_t)BB * H3 * 4;
  float* zsq  = (float*)(scratch + o2);                         // 48 KB

  // prepass: convert & transpose
  k_f2b<<<dim3(2048), dim3(256), 0, stream>>>(x, xbf, BB * TT * EE / 4);
  k_transpose_f2b<<<dim3(DD / 32, (DD + EE) / 32, 1), dim3(256), 0, stream>>>(W_in, WT, DD + EE, DD);
  k_transpose_f2b<<<dim3(CH / 32, (DD / GG) / 32, GG), dim3(256), 0, stream>>>(W_blk, WbT, DD / GG, CH);
  k_initdet<<<dim3(BB * DD / 4 / 256), dim3(256), 0, stream>>>(deter0, dF, dB, BB * DD / 4);

  // P1: Xproj = x @ W2 + b_in -> bf16   (M=4096, K=2048, N=4096); 1D grid + XCD swizzle
  k_p1<<<dim3(1024), dim3(256), 0, stream>>>(
      xbf, WT + DD, b_in, Xproj);

  // scan: 4 dispatches/step (proven fastest sync structure)
  for (int t = 0; t < TT; t++) {
    kA<<<dim3(64, 4), dim3(512), 0, stream>>>(dB, WT, part);
    kB<<<dim3(BB), dim3(512), 0, stream>>>(part, Xproj, scale_in, ybf, t);
    kC<<<dim3(192), dim3(256), 0, stream>>>(ybf, WbT, b_blk, zbuf, zsq);
    kD<<<dim3(256), dim3(256), 0, stream>>>(zbuf, zsq, scale_blk, dF, dB, out, t);
  }
}

// Round 16
// 1768.707 us; speedup vs baseline: 1.0593x; 1.0593x over previous
//
#include <hip/hip_runtime.h>

typedef unsigned short u16;
typedef unsigned int u32;
typedef __bf16 bfx8 __attribute__((ext_vector_type(8)));
typedef float f32x4 __attribute__((ext_vector_type(4)));

constexpr int BB = 64;     // batch
constexpr int TT = 64;     // time
constexpr int EE = 2048;   // x feature
constexpr int DD = 4096;   // deter
constexpr int GG = 8;      // groups
constexpr int H3 = 3 * DD;       // 12288
constexpr int CH = H3 / GG;      // 1536
constexpr float EPSf = 1e-4f;

static __device__ __forceinline__ u16 f2bf(float f) {
  u32 u = __builtin_bit_cast(u32, f);
  u32 r = (u + 0x7fffu + ((u >> 16) & 1u)) >> 16;
  return (u16)r;
}
static __device__ __forceinline__ float bf2f(u16 h) {
  return __builtin_bit_cast(float, (u32)h << 16);
}

// async global->LDS, 16B per lane; LDS dest = wave-uniform base + lane*16
#define GLOAD_LDS16(gp, lp)                                                    \
  __builtin_amdgcn_global_load_lds(                                           \
      (const __attribute__((address_space(1))) void*)(gp),                    \
      (__attribute__((address_space(3))) void*)(lp), 16, 0, 0)

// ---------------- prepass kernels ----------------

__global__ void __launch_bounds__(256) k_f2b(const float* __restrict__ in,
                                             u16* __restrict__ out, int n4) {
  int i = blockIdx.x * 256 + threadIdx.x;
  int stride = gridDim.x * 256;
  for (; i < n4; i += stride) {
    float4 v = ((const float4*)in)[i];
    uint2 o;
    o.x = (u32)f2bf(v.x) | ((u32)f2bf(v.y) << 16);
    o.y = (u32)f2bf(v.z) | ((u32)f2bf(v.w) << 16);
    ((uint2*)out)[i] = o;
  }
}

__global__ void __launch_bounds__(256) k_initdet(const float* __restrict__ d0,
                                                 float* __restrict__ dF,
                                                 u16* __restrict__ dB, int n4) {
  int i = blockIdx.x * 256 + threadIdx.x;
  if (i < n4) {
    float4 v = ((const float4*)d0)[i];
    ((float4*)dF)[i] = v;
    uint2 o;
    o.x = (u32)f2bf(v.x) | ((u32)f2bf(v.y) << 16);
    o.y = (u32)f2bf(v.z) | ((u32)f2bf(v.w) << 16);
    ((uint2*)dB)[i] = o;
  }
}

// in [R][C] f32 -> out [C][R] bf16  (batched over blockIdx.z)
__global__ void __launch_bounds__(256) k_transpose_f2b(const float* __restrict__ in,
                                                       u16* __restrict__ out,
                                                       int R, int C) {
  __shared__ float tile[32][33];
  size_t base = (size_t)blockIdx.z * R * C;
  in += base; out += base;
  int tx = threadIdx.x & 31, ty = threadIdx.x >> 5;
  int r0 = blockIdx.y * 32, c0 = blockIdx.x * 32;
#pragma unroll
  for (int i = 0; i < 4; i++) {
    int rr = ty * 4 + i;
    tile[rr][tx] = in[(size_t)(r0 + rr) * C + (c0 + tx)];
  }
  __syncthreads();
#pragma unroll
  for (int i = 0; i < 4; i++) {
    int cc = ty * 4 + i;
    out[(size_t)(c0 + cc) * R + (r0 + tx)] = f2bf(tile[tx][cc]);
  }
}

// ---------------- P1: Xproj = x @ W2 + b_in -> bf16 ----------------
// m97 structure + T2 swizzle: linear LDS dest (global_load_lds), source col
// pre-swizzled (slot ^= row&7), ds_read slot swizzled identically.
// Round-14 proven configuration (2D grid, default dispatch order).

__global__ void __launch_bounds__(256) k_p1(const u16* __restrict__ A,  // [4096][2048]
                                            const u16* __restrict__ B,  // [4096][6144] (W2T at col 0)
                                            const float* __restrict__ bias,
                                            u16* __restrict__ C) {      // [4096][4096] bf16
  __shared__ u16 As[128 * 64];   // 16 KB, linear [row][64]
  __shared__ u16 Bs[128 * 64];   // 16 KB
  const int tid = threadIdx.x;
  const int m0 = blockIdx.y * 128, n0 = blockIdx.x * 128;
  const int w = tid >> 6, lane = tid & 63;
  const int wr = w >> 1, wc = w & 1;
  const int lr = lane & 15, lk = (lane >> 4) * 8;
  // staging: chunk = w*4+i (8 rows x 8 slots); lane covers row chunk*8+(l>>3),
  // dest slot l&7; SOURCE col slot = (l&7) ^ (row&7) = (l&7) ^ (l>>3).
  const int lrow = lane >> 3;
  const int lcol = (((lane & 7) ^ (lane >> 3)) << 3);
  const u16* gA[4];
  const u16* gB[4];
  u16* lA[4];
  u16* lB[4];
#pragma unroll
  for (int i = 0; i < 4; i++) {
    const int chunk = w * 4 + i;
    const int row = chunk * 8 + lrow;
    gA[i] = A + (size_t)(m0 + row) * EE + lcol;
    gB[i] = B + (size_t)(n0 + row) * (DD + EE) + lcol;
    lA[i] = &As[chunk * 512];
    lB[i] = &Bs[chunk * 512];
  }

  f32x4 acc[4][4] = {};

  for (int kt = 0; kt < EE; kt += 64) {
#pragma unroll
    for (int i = 0; i < 4; i++) {
      GLOAD_LDS16(gA[i] + kt, lA[i]);
      GLOAD_LDS16(gB[i] + kt, lB[i]);
    }
    __syncthreads();   // drains vmcnt (async loads) before LDS reads
#pragma unroll
    for (int kk = 0; kk < 64; kk += 32) {
      const int sl = (((kk + lk) >> 3) ^ (lr & 7)) << 3;  // swizzled slot offset
      bfx8 av[4], bv[4];
#pragma unroll
      for (int mi = 0; mi < 4; mi++)
        av[mi] = *(const bfx8*)&As[(wr * 64 + mi * 16 + lr) * 64 + sl];
#pragma unroll
      for (int ni = 0; ni < 4; ni++)
        bv[ni] = *(const bfx8*)&Bs[(wc * 64 + ni * 16 + lr) * 64 + sl];
#pragma unroll
      for (int mi = 0; mi < 4; mi++)
#pragma unroll
        for (int ni = 0; ni < 4; ni++)
          acc[mi][ni] = __builtin_amdgcn_mfma_f32_16x16x32_bf16(av[mi], bv[ni], acc[mi][ni], 0, 0, 0);
    }
    __syncthreads();
  }

  const int rq = (lane >> 4) * 4;
#pragma unroll
  for (int mi = 0; mi < 4; mi++) {
#pragma unroll
    for (int ni = 0; ni < 4; ni++) {
      const int n = n0 + wc * 64 + ni * 16 + lr;
      const float bias_v = bias[n];
#pragma unroll
      for (int r = 0; r < 4; r++) {
        const int m = m0 + wr * 64 + mi * 16 + rq + r;
        C[(size_t)m * DD + n] = f2bf(acc[mi][ni][r] + bias_v);
      }
    }
  }
}

// ---------------- scan kernels ----------------
// kA: part[kc] = dB @ W1[:, kc*1024 .. +1024]   (round-14 proven body)
// global_load_lds staging, linear [64][128] LDS, dbuf, 1 barrier/iter,
// both-sides XOR swizzle.

__global__ void __launch_bounds__(512) kA(const u16* __restrict__ dB,
                                          const u16* __restrict__ WT,
                                          float* __restrict__ part) {
  __shared__ u16 As[2 * 8192];   // 32 KB
  __shared__ u16 Bs[2 * 8192];   // 32 KB
  const int tid = threadIdx.x;
  const int n0 = blockIdx.x * 64;
  const int k0 = blockIdx.y * 1024;
  const int w = tid >> 6, lane = tid & 63;
  const int wr = w >> 1, wc = w & 1;
  const int lr = lane & 15, lk = (lane >> 4) * 8, rq = (lane >> 4) * 4;
  const int r0 = w * 4 + (lane >> 4);          // rows 0..31 (half 0)
  const int r1 = r0 + 32;                      // rows 32..63 (half 1)
  const int s0 = (((lane & 15) ^ (r0 & 15)) << 3);
  const int s1 = (((lane & 15) ^ (r1 & 15)) << 3);
  const u16* gA0 = dB + (size_t)r0 * DD + k0 + s0;
  const u16* gA1 = dB + (size_t)r1 * DD + k0 + s1;
  const u16* gB0 = WT + (size_t)(n0 + r0) * (DD + EE) + k0 + s0;
  const u16* gB1 = WT + (size_t)(n0 + r1) * (DD + EE) + k0 + s1;
  u16* dA0 = &As[0] + w * 512;
  u16* dA1 = &As[0] + 4096 + w * 512;
  u16* dB0 = &Bs[0] + w * 512;
  u16* dB1 = &Bs[0] + 4096 + w * 512;

  f32x4 acc[2] = {};
  GLOAD_LDS16(gA0, dA0);
  GLOAD_LDS16(gA1, dA1);
  GLOAD_LDS16(gB0, dB0);
  GLOAD_LDS16(gB1, dB1);
  __syncthreads();

  for (int kt = 0; kt < 8; ++kt) {
    const int p = kt & 1, q = p ^ 1;
    if (kt < 7) {
      const int ko = (kt + 1) * 128;
      GLOAD_LDS16(gA0 + ko, dA0 + q * 8192);
      GLOAD_LDS16(gA1 + ko, dA1 + q * 8192);
      GLOAD_LDS16(gB0 + ko, dB0 + q * 8192);
      GLOAD_LDS16(gB1 + ko, dB1 + q * 8192);
    }
    const u16* ab = &As[p * 8192];
    const u16* bb = &Bs[p * 8192];
#pragma unroll
    for (int kk = 0; kk < 128; kk += 32) {
      const int sl = ((((kk + lk) >> 3)) ^ lr) << 3;   // swizzled slot offset
      bfx8 av = *(const bfx8*)&ab[(wr * 16 + lr) * 128 + sl];
#pragma unroll
      for (int ni = 0; ni < 2; ni++) {
        bfx8 bv = *(const bfx8*)&bb[(wc * 32 + ni * 16 + lr) * 128 + sl];
        acc[ni] = __builtin_amdgcn_mfma_f32_16x16x32_bf16(av, bv, acc[ni], 0, 0, 0);
      }
    }
    __syncthreads();
  }

  float* Pp = part + (size_t)blockIdx.y * BB * DD;
#pragma unroll
  for (int ni = 0; ni < 2; ni++)
#pragma unroll
    for (int r = 0; r < 4; r++)
      Pp[(size_t)(wr * 16 + rq + r) * DD + n0 + wc * 32 + ni * 16 + lr] = acc[ni][r];
}

// kB: y = silu(rms(sum_kc part + Xproj_t) * scale_in) -> bf16   grid 64 x 512 thr
__global__ void __launch_bounds__(512) kB(const float* __restrict__ part,
                                          const u16* __restrict__ Xproj,
                                          const float* __restrict__ scale_in,
                                          u16* __restrict__ ybf, int t) {
  const int b = blockIdx.x, tid = threadIdx.x;
  const int w = tid >> 6, lane = tid & 63;
  __shared__ float sred[8];
  const u16* xp = Xproj + ((size_t)b * TT + t) * DD + tid * 8;
  const float* pb = part + (size_t)b * DD + tid * 8;
  float v[8];
  uint4 x0 = *(const uint4*)(xp);
#pragma unroll
  for (int j = 0; j < 8; j++) v[j] = bf2f(((const u16*)&x0)[j]);
#pragma unroll
  for (int kc = 0; kc < 4; kc++) {
    const float* p = pb + (size_t)kc * BB * DD;
    float4 q0 = *(const float4*)(p);
    float4 q1 = *(const float4*)(p + 4);
    v[0] += q0.x; v[1] += q0.y; v[2] += q0.z; v[3] += q0.w;
    v[4] += q1.x; v[5] += q1.y; v[6] += q1.z; v[7] += q1.w;
  }
  float ss = 0.f;
#pragma unroll
  for (int j = 0; j < 8; j++) ss += v[j] * v[j];
#pragma unroll
  for (int o = 32; o > 0; o >>= 1) ss += __shfl_down(ss, o);
  if (lane == 0) sred[w] = ss;
  __syncthreads();
  float tot = 0.f;
#pragma unroll
  for (int i = 0; i < 8; i++) tot += sred[i];
  const float r = rsqrtf(tot / (float)DD + EPSf);
  const float* sc = scale_in + tid * 8;
  u32 pk[4];
#pragma unroll
  for (int j = 0; j < 4; j++) {
    float a = v[2 * j] * r * sc[2 * j];
    float bq = v[2 * j + 1] * r * sc[2 * j + 1];
    a = a / (1.f + __expf(-a));
    bq = bq / (1.f + __expf(-bq));
    pk[j] = (u32)f2bf(a) | ((u32)f2bf(bq) << 16);
  }
  *(uint4*)(ybf + (size_t)b * DD + tid * 8) = make_uint4(pk[0], pk[1], pk[2], pk[3]);
}

// kC: z = blockdiag(y @ Wblk) + b_blk -> zbuf f32; fused per-row sumsq -> zsq[192][64]
// (round-11/14 proven body: reg-staged padded LDS dbuf, 1 barrier/iter)
constexpr int LSC2 = 72;
constexpr int CBUF = 64 * LSC2;

__global__ void __launch_bounds__(256) kC(const u16* __restrict__ ybf,
                                          const u16* __restrict__ WbT,
                                          const float* __restrict__ b_blk,
                                          float* __restrict__ zbuf,
                                          float* __restrict__ zsq) {
  __shared__ u16 As[2 * CBUF];
  __shared__ u16 Bs[2 * CBUF];
  const int tid = threadIdx.x;
  const int wg = blockIdx.x;
  const int n0g = wg * 64;
  const int g = n0g / CH, nl = n0g % CH;
  const int w = tid >> 6, lane = tid & 63;
  const int lr = lane & 15, lk = (lane >> 4) * 8, rq = (lane >> 4) * 4;
  const int srow = tid >> 2, sc = (tid & 3) * 8;
  const u16* Arow = ybf + (size_t)srow * DD + g * (DD / GG) + sc;
  const u16* Brow = WbT + ((size_t)g * CH + nl + srow) * (DD / GG) + sc;
  const int dA = srow * LSC2 + sc;

  f32x4 acc[4] = {};
  uint4 ra0 = *(const uint4*)(Arow);
  uint4 ra1 = *(const uint4*)(Arow + 32);
  uint4 rb0 = *(const uint4*)(Brow);
  uint4 rb1 = *(const uint4*)(Brow + 32);

  for (int kt = 0; kt < 8; ++kt) {
    const int p = kt & 1;
    u16* ab = As + p * CBUF;
    u16* bb = Bs + p * CBUF;
    *(uint4*)&ab[dA] = ra0;
    *(uint4*)&ab[dA + 32] = ra1;
    *(uint4*)&bb[dA] = rb0;
    *(uint4*)&bb[dA + 32] = rb1;
    __syncthreads();
    if (kt < 7) {
      const int ko = (kt + 1) * 64;
      ra0 = *(const uint4*)(Arow + ko);
      ra1 = *(const uint4*)(Arow + ko + 32);
      rb0 = *(const uint4*)(Brow + ko);
      rb1 = *(const uint4*)(Brow + ko + 32);
    }
#pragma unroll
    for (int kk = 0; kk < 64; kk += 32) {
      bfx8 av = *(const bfx8*)&ab[(w * 16 + lr) * LSC2 + kk + lk];
#pragma unroll
      for (int ni = 0; ni < 4; ni++) {
        bfx8 bv = *(const bfx8*)&bb[(ni * 16 + lr) * LSC2 + kk + lk];
        acc[ni] = __builtin_amdgcn_mfma_f32_16x16x32_bf16(av, bv, acc[ni], 0, 0, 0);
      }
    }
  }

  float sq[4] = {0.f, 0.f, 0.f, 0.f};
#pragma unroll
  for (int ni = 0; ni < 4; ni++) {
    const int n = n0g + ni * 16 + lr;
    const float bias_v = b_blk[n];
#pragma unroll
    for (int r = 0; r < 4; r++) {
      const float zv = acc[ni][r] + bias_v;
      zbuf[(size_t)(w * 16 + rq + r) * H3 + n] = zv;
      sq[r] += zv * zv;
    }
  }
#pragma unroll
  for (int o = 1; o < 16; o <<= 1) {
#pragma unroll
    for (int r = 0; r < 4; r++) sq[r] += __shfl_xor(sq[r], o);
  }
  if (lr == 0) {
#pragma unroll
    for (int r = 0; r < 4; r++) zsq[(size_t)wg * 64 + w * 16 + rq + r] = sq[r];
  }
}

// kD: block-rms + gates + deter update + out write   grid 256 (= 64 b x 4 col-slices)
__global__ void __launch_bounds__(256) kD(const float* __restrict__ zbuf,
                                          const float* __restrict__ zsq,
                                          const float* __restrict__ sblk,
                                          float* __restrict__ dF,
                                          u16* __restrict__ dB,
                                          float* __restrict__ out, int t) {
  const int wg = blockIdx.x, tid = threadIdx.x;
  const int b = wg >> 2, s = wg & 3;
  __shared__ float sred[8];
  if (tid < 8) {
    float ssq = 0.f;
    const int j0 = tid * 24;
#pragma unroll
    for (int j = 0; j < 24; j++) ssq += zsq[(size_t)(j0 + j) * 64 + b];
    sred[tid] = rsqrtf(ssq / (float)CH + EPSf);
  }
  __syncthreads();
  const int d0 = s * 1024 + tid * 4;
  const float* zr = zbuf + (size_t)b * H3;
  float4 z0 = *(const float4*)(zr + d0);
  float4 z1 = *(const float4*)(zr + DD + d0);
  float4 z2 = *(const float4*)(zr + 2 * DD + d0);
  float4 dold = *(const float4*)(dF + (size_t)b * DD + d0);
  const float rsA = sred[d0 / CH];
  const float rsB = sred[(DD + d0) / CH];
  const float rsC = sred[(2 * DD + d0) / CH];
  float dn[4];
  const float* z0p = (const float*)&z0;
  const float* z1p = (const float*)&z1;
  const float* z2p = (const float*)&z2;
  const float* dop = (const float*)&dold;
#pragma unroll
  for (int e = 0; e < 4; e++) {
    const int dd = d0 + e;
    const float a0 = z0p[e] * rsA * sblk[dd];
    const float a1 = z1p[e] * rsB * sblk[DD + dd];
    const float a2 = z2p[e] * rsC * sblk[2 * DD + dd];
    const float reset = 1.f / (1.f + __expf(-a0));
    const float cand = tanhf(reset * a1);
    const float upd = 1.f / (1.f + __expf(-(a2 - 1.f)));
    dn[e] = upd * cand + (1.f - upd) * dop[e];
  }
  *(float4*)(dF + (size_t)b * DD + d0) = make_float4(dn[0], dn[1], dn[2], dn[3]);
  uint2 o;
  o.x = (u32)f2bf(dn[0]) | ((u32)f2bf(dn[1]) << 16);
  o.y = (u32)f2bf(dn[2]) | ((u32)f2bf(dn[3]) << 16);
  *(uint2*)(dB + (size_t)b * DD + d0) = o;
  *(float4*)(out + ((size_t)b * TT + t) * DD + d0) = make_float4(dn[0], dn[1], dn[2], dn[3]);
}

// ---------------- host ----------------

extern "C" void kernel_launch(void* const* d_in, const int* in_sizes, int n_in,
                              void* d_out, int out_size, void* d_ws, size_t ws_size,
                              hipStream_t stream) {
  (void)in_sizes; (void)n_in; (void)out_size; (void)ws_size;
  const float* x         = (const float*)d_in[0];  // [B,T,E]
  const float* deter0    = (const float*)d_in[1];  // [B,D]
  const float* W_in      = (const float*)d_in[2];  // [D+E, D]
  const float* b_in      = (const float*)d_in[3];  // [D]
  const float* scale_in  = (const float*)d_in[4];  // [D]
  const float* W_blk     = (const float*)d_in[5];  // [G, D/G, 3D/G]
  const float* b_blk     = (const float*)d_in[6];  // [3D]
  const float* scale_blk = (const float*)d_in[7];  // [G, 3D/G]
  float* out = (float*)d_out;

  char* ws = (char*)d_ws;
  size_t off = 0;
  auto alloc = [&](size_t bytes) -> void* {
    void* p = ws + off;
    off += (bytes + 255) & ~(size_t)255;
    return p;
  };
  u16*   WT    = (u16*)alloc((size_t)DD * (DD + EE) * 2);       // 50.3 MB
  u16*   WbT   = (u16*)alloc((size_t)GG * CH * (DD / GG) * 2);  // 12.6 MB
  u16*   Xproj = (u16*)alloc((size_t)BB * TT * DD * 2);         // 32 MB (bf16)
  float* dF    = (float*)alloc((size_t)BB * DD * 4);            // 1 MB
  u16*   dB    = (u16*)alloc((size_t)BB * DD * 2);              // 0.5 MB
  // scratch region: xbf (prepass/P1 only) aliases scan-only buffers
  char* scratch = (char*)alloc((size_t)BB * TT * EE * 2);       // 16.8 MB
  u16*   xbf  = (u16*)scratch;
  float* part = (float*)scratch;                                // 4 MB (4 splits)
  size_t o2 = (size_t)4 * BB * DD * 4;
  u16*   ybf  = (u16*)(scratch + o2);                           // 0.5 MB
  o2 += (size_t)BB * DD * 2;
  float* zbuf = (float*)(scratch + o2);                         // 3 MB
  o2 += (size_t)BB * H3 * 4;
  float* zsq  = (float*)(scratch + o2);                         // 48 KB

  // prepass: convert & transpose
  k_f2b<<<dim3(2048), dim3(256), 0, stream>>>(x, xbf, BB * TT * EE / 4);
  k_transpose_f2b<<<dim3(DD / 32, (DD + EE) / 32, 1), dim3(256), 0, stream>>>(W_in, WT, DD + EE, DD);
  k_transpose_f2b<<<dim3(CH / 32, (DD / GG) / 32, GG), dim3(256), 0, stream>>>(W_blk, WbT, DD / GG, CH);
  k_initdet<<<dim3(BB * DD / 4 / 256), dim3(256), 0, stream>>>(deter0, dF, dB, BB * DD / 4);

  // P1: Xproj = x @ W2 + b_in -> bf16   (M=4096, K=2048, N=4096)
  k_p1<<<dim3(DD / 128, BB * TT / 128), dim3(256), 0, stream>>>(
      xbf, WT + DD, b_in, Xproj);

  // scan: 4 dispatches/step (proven fastest sync structure)
  for (int t = 0; t < TT; t++) {
    kA<<<dim3(64, 4), dim3(512), 0, stream>>>(dB, WT, part);
    kB<<<dim3(BB), dim3(512), 0, stream>>>(part, Xproj, scale_in, ybf, t);
    kC<<<dim3(192), dim3(256), 0, stream>>>(ybf, WbT, b_blk, zbuf, zsq);
    kD<<<dim3(256), dim3(256), 0, stream>>>(zbuf, zsq, scale_blk, dF, dB, out, t);
  }
}